// Round 1
// baseline (343.286 us; speedup 1.0000x reference)
//
#include <hip/hip_runtime.h>
#include <hip/hip_bf16.h>

// Problem constants: B=4,T=8,L=512,C=768,H=8,HD=96
// M = B*T*L = 16384 rows of x.

typedef __attribute__((ext_vector_type(8))) short bf16x8;
typedef __attribute__((ext_vector_type(4))) float f32x4;
typedef __attribute__((ext_vector_type(4))) int int4v;

__device__ __forceinline__ float b2f(unsigned short u) {
    return __uint_as_float(((unsigned)u) << 16);
}
__device__ __forceinline__ unsigned short f2b(float f) {
    unsigned u = __float_as_uint(f);
    u = (u + 0x7fffu + ((u >> 16) & 1u)) >> 16;   // RNE
    return (unsigned short)u;
}

// ---------------- cast x (fp32) -> bf16 ----------------
__global__ __launch_bounds__(256) void cast_bf16_k(const float* __restrict__ x,
                                                   unsigned short* __restrict__ xb, int n4) {
    int i = blockIdx.x * 256 + threadIdx.x;
    if (i >= n4) return;
    float4 v = ((const float4*)x)[i];
    ushort4 o;
    o.x = f2b(v.x); o.y = f2b(v.y); o.z = f2b(v.z); o.w = f2b(v.w);
    ((ushort4*)xb)[i] = o;
}

// ---------------- pack weights: Wt[n][k] = W[k][n] (bf16), n in [0,3072) ----------------
// n 0..767 -> Wq, 768..2303 -> Wkv, 2304..3071 -> Wm. All K=768.
__global__ __launch_bounds__(256) void pack_w_k(const float* __restrict__ Wq,
                                                const float* __restrict__ Wkv,
                                                const float* __restrict__ Wm,
                                                unsigned short* __restrict__ Wt) {
    __shared__ float tile[64][65];
    const int tid = threadIdx.x;
    const int tn = blockIdx.x % 48;   // 3072/64
    const int tk = blockIdx.x / 48;   // 768/64
    const int n0 = tn * 64, k0 = tk * 64;
    const float* src; int ldn, coff;
    if (n0 < 768)       { src = Wq;  ldn = 768;  coff = n0; }
    else if (n0 < 2304) { src = Wkv; ldn = 1536; coff = n0 - 768; }
    else                { src = Wm;  ldn = 768;  coff = n0 - 2304; }
    const int j = tid & 63;
    for (int i = tid >> 6; i < 64; i += 4)
        tile[i][j] = src[(k0 + i) * ldn + coff + j];
    __syncthreads();
    const int ii = tid & 63;
    for (int jj = tid >> 6; jj < 64; jj += 4)
        Wt[(long)(n0 + jj) * 768 + k0 + ii] = f2b(tile[ii][jj]);
}

// ---------------- GEMM: C = A(MxK,bf16) * Bt(NxK,bf16)^T + bias ----------------
// EPI 0: bf16 out, bias = col<768 ? bias0[col] : bias1[col-768]
// EPI 1: fp32 out, bias = bias0[col]
template <int EPI>
__global__ __launch_bounds__(256) void gemm_bt_k(const unsigned short* __restrict__ A,
                                                 const unsigned short* __restrict__ Bt,
                                                 const float* __restrict__ bias0,
                                                 const float* __restrict__ bias1,
                                                 unsigned short* __restrict__ Cb,
                                                 float* __restrict__ Cf,
                                                 int M, int N, int K) {
    constexpr int BM = 128, BN = 128, BK = 32, LDT = 40;  // LDT padded (16B-aligned rows)
    __shared__ unsigned short As[BM * LDT];
    __shared__ unsigned short Bs[BN * LDT];
    const int tid = threadIdx.x;
    const int lane = tid & 63, wid = tid >> 6;
    const int wr = wid >> 1, wc = wid & 1;
    const int tn = N / BN;
    const int bm = blockIdx.x / tn, bn = blockIdx.x % tn;

    f32x4 acc[4][4] = {};

    const int c0 = tid, c1 = tid + 256;
    const int r0 = c0 >> 2, o0 = (c0 & 3) * 8;
    const int r1 = c1 >> 2, o1 = (c1 & 3) * 8;
    const long aoff0 = (long)(bm * BM + r0) * K;
    const long aoff1 = (long)(bm * BM + r1) * K;
    const long boff0 = (long)(bn * BN + r0) * K;
    const long boff1 = (long)(bn * BN + r1) * K;
    const int l15 = lane & 15;
    const int ko = (lane >> 4) * 8;

    for (int kt = 0; kt < K; kt += BK) {
        *(int4v*)&As[r0 * LDT + o0] = *(const int4v*)&A[aoff0 + kt + o0];
        *(int4v*)&As[r1 * LDT + o1] = *(const int4v*)&A[aoff1 + kt + o1];
        *(int4v*)&Bs[r0 * LDT + o0] = *(const int4v*)&Bt[boff0 + kt + o0];
        *(int4v*)&Bs[r1 * LDT + o1] = *(const int4v*)&Bt[boff1 + kt + o1];
        __syncthreads();
        bf16x8 af[4], bfr[4];
#pragma unroll
        for (int mf = 0; mf < 4; mf++)
            af[mf] = *(const bf16x8*)&As[(wr * 64 + mf * 16 + l15) * LDT + ko];
#pragma unroll
        for (int nf = 0; nf < 4; nf++)
            bfr[nf] = *(const bf16x8*)&Bs[(wc * 64 + nf * 16 + l15) * LDT + ko];
#pragma unroll
        for (int mf = 0; mf < 4; mf++)
#pragma unroll
            for (int nf = 0; nf < 4; nf++)
                acc[mf][nf] = __builtin_amdgcn_mfma_f32_16x16x32_bf16(af[mf], bfr[nf], acc[mf][nf], 0, 0, 0);
        __syncthreads();
    }

#pragma unroll
    for (int mf = 0; mf < 4; mf++) {
#pragma unroll
        for (int nf = 0; nf < 4; nf++) {
#pragma unroll
            for (int r = 0; r < 4; r++) {
                const int row = bm * BM + wr * 64 + mf * 16 + (lane >> 4) * 4 + r;
                const int col = bn * BN + wc * 64 + nf * 16 + l15;
                float v = acc[mf][nf][r];
                if (EPI == 0) {
                    float b = (col < 768) ? bias0[col] : bias1[col - 768];
                    Cb[(long)row * N + col] = f2b(v + b);
                } else {
                    Cf[(long)row * N + col] = v + bias0[col];
                }
            }
        }
    }
}

// ---------------- L2 normalize each 96-element segment of each qkv row ----------------
// qkv: 16384 x 2304 bf16; 24 segments per row; one wave per segment.
__global__ __launch_bounds__(256) void l2norm_k(unsigned short* __restrict__ qkv) {
    const int tid = threadIdx.x, lane = tid & 63, w = tid >> 6;
    const int g = blockIdx.x * 4 + w;                 // 0 .. 16384*24-1
    const int row = g / 24, seg = g % 24;
    unsigned short* p = qkv + (long)row * 2304 + seg * 96;
    float f0 = 0.f, f1 = 0.f;
    if (lane < 48) {
        unsigned v = *(const unsigned*)(p + lane * 2);
        f0 = b2f((unsigned short)(v & 0xffffu));
        f1 = b2f((unsigned short)(v >> 16));
    }
    float ss = f0 * f0 + f1 * f1;
#pragma unroll
    for (int m = 1; m < 64; m <<= 1) ss += __shfl_xor(ss, m);
    const float sc = 1.f / fmaxf(sqrtf(ss), 1e-12f);
    if (lane < 48) {
        unsigned o = (unsigned)f2b(f0 * sc) | ((unsigned)f2b(f1 * sc) << 16);
        *(unsigned*)(p + lane * 2) = o;
    }
}

// ---------------- fused attention per (bt, head, qtile) ----------------
// qkv rows: bt*512 + l, cols: q at h*96, k at 768+h*96, v at 1536+h*96.
// obuf: 16384 x 768 bf16, (b,t,l,c) layout.
__global__ __launch_bounds__(256) void attn_k(const unsigned short* __restrict__ qkv,
                                              unsigned short* __restrict__ obuf) {
    constexpr float SCALE = 0.1020620726159658f;  // 1/sqrt(96)
    __shared__ unsigned short Qs[64][104];
    __shared__ unsigned short Ks[64][104];
    __shared__ unsigned short Vts[96][72];
    __shared__ float Ss[64][65];
    __shared__ unsigned short Ps[64][72];
    __shared__ float mrow[64], lrow[64], arow[64];

    const int tid = threadIdx.x, lane = tid & 63, w = tid >> 6;
    const int bid = blockIdx.x;
    const int qt = bid & 7, h = (bid >> 3) & 7, bt = bid >> 6;
    const long rowbase = (long)bt * 512 * 2304;
    const int l15 = lane & 15;
    const int ko = (lane >> 4) * 8;

    // load Q tile (64 x 96)
    for (int c = tid; c < 768; c += 256) {
        const int r = c / 12, d8 = (c % 12) * 8;
        *(int4v*)&Qs[r][d8] = *(const int4v*)&qkv[rowbase + (long)(qt * 64 + r) * 2304 + h * 96 + d8];
    }
    if (tid < 64) { mrow[tid] = -3.0e38f; lrow[tid] = 0.f; }
    f32x4 oacc[6] = {};

    for (int kt = 0; kt < 8; kt++) {
        // load K tile and V tile (transposed)
        for (int c = tid; c < 768; c += 256) {
            const int r = c / 12, d8 = (c % 12) * 8;
            const long g = rowbase + (long)(kt * 64 + r) * 2304 + h * 96 + d8;
            *(int4v*)&Ks[r][d8] = *(const int4v*)&qkv[g + 768];
            int4v vv = *(const int4v*)&qkv[g + 1536];
            const unsigned short* vp = (const unsigned short*)&vv;
#pragma unroll
            for (int i = 0; i < 8; i++) Vts[d8 + i][r] = vp[i];
        }
        __syncthreads();

        // S = Q K^T  (wave w: rows w*16..w*16+15)
        f32x4 sacc[4] = {};
#pragma unroll
        for (int ks = 0; ks < 3; ks++) {
            bf16x8 af = *(const bf16x8*)&Qs[w * 16 + l15][ks * 32 + ko];
#pragma unroll
            for (int nf = 0; nf < 4; nf++) {
                bf16x8 bfr = *(const bf16x8*)&Ks[nf * 16 + l15][ks * 32 + ko];
                sacc[nf] = __builtin_amdgcn_mfma_f32_16x16x32_bf16(af, bfr, sacc[nf], 0, 0, 0);
            }
        }
#pragma unroll
        for (int nf = 0; nf < 4; nf++)
#pragma unroll
            for (int r = 0; r < 4; r++)
                Ss[w * 16 + (lane >> 4) * 4 + r][nf * 16 + l15] = sacc[nf][r] * SCALE;
        __syncthreads();

        // online softmax: thread t handles row t>>2, 16 cols at (t&3)*16
        {
            const int r = tid >> 2, q4 = tid & 3;
            float vals[16];
            float mx = -3.0e38f;
#pragma unroll
            for (int i = 0; i < 16; i++) { vals[i] = Ss[r][q4 * 16 + i]; mx = fmaxf(mx, vals[i]); }
            mx = fmaxf(mx, __shfl_xor(mx, 1));
            mx = fmaxf(mx, __shfl_xor(mx, 2));
            const float mold = mrow[r];
            const float mnew = fmaxf(mold, mx);
            const float al = __expf(mold - mnew);
            float s = 0.f;
#pragma unroll
            for (int i = 0; i < 16; i++) {
                float pv = __expf(vals[i] - mnew);
                s += pv;
                Ps[r][q4 * 16 + i] = f2b(pv);
            }
            s += __shfl_xor(s, 1);
            s += __shfl_xor(s, 2);
            if (q4 == 0) { lrow[r] = lrow[r] * al + s; mrow[r] = mnew; arow[r] = al; }
        }
        __syncthreads();

        // O = O*alpha + P V   (wave w: rows w*16..w*16+15, cols 0..95)
        {
            float alr[4];
#pragma unroll
            for (int r = 0; r < 4; r++) alr[r] = arow[w * 16 + (lane >> 4) * 4 + r];
#pragma unroll
            for (int nf = 0; nf < 6; nf++)
#pragma unroll
                for (int r = 0; r < 4; r++) oacc[nf][r] *= alr[r];
#pragma unroll
            for (int ks = 0; ks < 2; ks++) {
                bf16x8 pa = *(const bf16x8*)&Ps[w * 16 + l15][ks * 32 + ko];
#pragma unroll
                for (int nf = 0; nf < 6; nf++) {
                    bf16x8 vb = *(const bf16x8*)&Vts[nf * 16 + l15][ks * 32 + ko];
                    oacc[nf] = __builtin_amdgcn_mfma_f32_16x16x32_bf16(pa, vb, oacc[nf], 0, 0, 0);
                }
            }
        }
        __syncthreads();
    }

    // write O tile
#pragma unroll
    for (int r = 0; r < 4; r++) {
        const int row = w * 16 + (lane >> 4) * 4 + r;
        const float inv = 1.f / lrow[row];
        const long gr = ((long)(bt * 512 + qt * 64 + row)) * 768 + h * 96;
#pragma unroll
        for (int nf = 0; nf < 6; nf++)
            obuf[gr + nf * 16 + l15] = f2b(oacc[nf][r] * inv);
    }
}

extern "C" void kernel_launch(void* const* d_in, const int* in_sizes, int n_in,
                              void* d_out, int out_size, void* d_ws, size_t ws_size,
                              hipStream_t stream) {
    const float* x   = (const float*)d_in[0];
    const float* Wq  = (const float*)d_in[1];
    const float* bq  = (const float*)d_in[2];
    const float* Wkv = (const float*)d_in[3];
    const float* bkv = (const float*)d_in[4];
    const float* Wm  = (const float*)d_in[5];
    const float* bm  = (const float*)d_in[6];
    float* out = (float*)d_out;

    char* ws = (char*)d_ws;
    unsigned short* xb  = (unsigned short*)ws;                   // 16384x768 bf16  = 25165824 B
    unsigned short* wt  = (unsigned short*)(ws + 25165824);      // 3072x768 bf16   =  4718592 B
    unsigned short* qkv = (unsigned short*)(ws + 29884416);      // 16384x2304 bf16 = 75497472 B
    unsigned short* ob  = (unsigned short*)(ws + 105381888);     // 16384x768 bf16  = 25165824 B

    // 1) cast x to bf16
    cast_bf16_k<<<dim3(12288), dim3(256), 0, stream>>>(x, xb, 3145728);
    // 2) pack transposed weights (bf16)
    pack_w_k<<<dim3(576), dim3(256), 0, stream>>>(Wq, Wkv, Wm, wt);
    // 3) QKV projection + bias
    gemm_bt_k<0><<<dim3(128 * 18), dim3(256), 0, stream>>>(xb, wt, bq, bkv, qkv, nullptr, 16384, 2304, 768);
    // 4) L2 normalize all 96-wide segments (q, k, v)
    l2norm_k<<<dim3(98304), dim3(256), 0, stream>>>(qkv);
    // 5) attention
    attn_k<<<dim3(2048), dim3(256), 0, stream>>>(qkv, ob);
    // 6) output projection + bias -> fp32
    gemm_bt_k<1><<<dim3(128 * 6), dim3(256), 0, stream>>>(ob, wt + (long)2304 * 768, bm, nullptr, nullptr, out, 16384, 768, 768);
}

// Round 2
// 275.091 us; speedup vs baseline: 1.2479x; 1.2479x over previous
//
#include <hip/hip_runtime.h>
#include <hip/hip_bf16.h>

// Problem constants: B=4,T=8,L=512,C=768,H=8,HD=96
// M = B*T*L = 16384 rows of x.

typedef __attribute__((ext_vector_type(8))) short bf16x8;
typedef __attribute__((ext_vector_type(4))) float f32x4;
typedef __attribute__((ext_vector_type(4))) int int4v;

__device__ __forceinline__ float b2f(unsigned short u) {
    return __uint_as_float(((unsigned)u) << 16);
}
__device__ __forceinline__ unsigned short f2b(float f) {
    unsigned u = __float_as_uint(f);
    u = (u + 0x7fffu + ((u >> 16) & 1u)) >> 16;   // RNE
    return (unsigned short)u;
}

__device__ __forceinline__ void gll16(const unsigned short* g, unsigned short* l) {
    __builtin_amdgcn_global_load_lds((const __attribute__((address_space(1))) unsigned int*)g,
                                     (__attribute__((address_space(3))) unsigned int*)l, 16, 0, 0);
}

// ---------------- cast x (fp32) -> bf16 ----------------
__global__ __launch_bounds__(256) void cast_bf16_k(const float* __restrict__ x,
                                                   unsigned short* __restrict__ xb, int n4) {
    int i = blockIdx.x * 256 + threadIdx.x;
    if (i >= n4) return;
    float4 v = ((const float4*)x)[i];
    ushort4 o;
    o.x = f2b(v.x); o.y = f2b(v.y); o.z = f2b(v.z); o.w = f2b(v.w);
    ((ushort4*)xb)[i] = o;
}

// ---------------- pack weights: Wt[n][k] = W[k][n] (bf16), n in [0,3072) ----------------
__global__ __launch_bounds__(256) void pack_w_k(const float* __restrict__ Wq,
                                                const float* __restrict__ Wkv,
                                                const float* __restrict__ Wm,
                                                unsigned short* __restrict__ Wt) {
    __shared__ float tile[64][65];
    const int tid = threadIdx.x;
    const int tn = blockIdx.x % 48;   // 3072/64
    const int tk = blockIdx.x / 48;   // 768/64
    const int n0 = tn * 64, k0 = tk * 64;
    const float* src; int ldn, coff;
    if (n0 < 768)       { src = Wq;  ldn = 768;  coff = n0; }
    else if (n0 < 2304) { src = Wkv; ldn = 1536; coff = n0 - 768; }
    else                { src = Wm;  ldn = 768;  coff = n0 - 2304; }
    const int j = tid & 63;
    for (int i = tid >> 6; i < 64; i += 4)
        tile[i][j] = src[(k0 + i) * ldn + coff + j];
    __syncthreads();
    const int ii = tid & 63;
    for (int jj = tid >> 6; jj < 64; jj += 4)
        Wt[(long)(n0 + jj) * 768 + k0 + ii] = f2b(tile[ii][jj]);
}

// ---------------- GEMM: C = A(MxK,bf16) * Bt(NxK,bf16)^T + bias ----------------
// m97-style: global_load_lds width-16 staging into linear [128][32] LDS.
// EPI 0: bf16 out, bias = col<768 ? bias0[col] : bias1[col-768]
// EPI 1: fp32 out, bias = bias0[col]
template <int EPI>
__global__ __launch_bounds__(256) void gemm_bt_k(const unsigned short* __restrict__ A,
                                                 const unsigned short* __restrict__ Bt,
                                                 const float* __restrict__ bias0,
                                                 const float* __restrict__ bias1,
                                                 unsigned short* __restrict__ Cb,
                                                 float* __restrict__ Cf,
                                                 int M, int N, int K) {
    constexpr int BM = 128, BN = 128, BK = 32;
    __shared__ unsigned short As[BM * BK];
    __shared__ unsigned short Bs[BN * BK];
    const int tid = threadIdx.x;
    const int lane = tid & 63, wid = tid >> 6;
    const int wr = wid >> 1, wc = wid & 1;
    const int tn = N / BN;
    const int bm = blockIdx.x / tn, bn = blockIdx.x % tn;

    f32x4 acc[4][4] = {};

    // staging geometry: each wave stages 32 rows of A and 32 rows of B (2 x 1KB chunks each)
    const int srow = lane >> 2;          // 0..15
    const int scol = (lane & 3) * 8;     // 0,8,16,24
    const unsigned short* gA = A  + (long)(bm * BM + wid * 32 + srow) * K + scol;
    const unsigned short* gB = Bt + (long)(bn * BN + wid * 32 + srow) * K + scol;
    unsigned short* lA = &As[wid * 1024];
    unsigned short* lB = &Bs[wid * 1024];

    const int l15 = lane & 15;
    const int ko = (lane >> 4) * 8;

    for (int kt = 0; kt < K; kt += BK) {
        gll16(gA + kt,          lA);
        gll16(gA + kt + 16 * K, lA + 512);
        gll16(gB + kt,          lB);
        gll16(gB + kt + 16 * K, lB + 512);
        __syncthreads();
        bf16x8 af[4], bfr[4];
#pragma unroll
        for (int mf = 0; mf < 4; mf++)
            af[mf] = *(const bf16x8*)&As[(wr * 64 + mf * 16 + l15) * BK + ko];
#pragma unroll
        for (int nf = 0; nf < 4; nf++)
            bfr[nf] = *(const bf16x8*)&Bs[(wc * 64 + nf * 16 + l15) * BK + ko];
#pragma unroll
        for (int mf = 0; mf < 4; mf++)
#pragma unroll
            for (int nf = 0; nf < 4; nf++)
                acc[mf][nf] = __builtin_amdgcn_mfma_f32_16x16x32_bf16(af[mf], bfr[nf], acc[mf][nf], 0, 0, 0);
        __syncthreads();
    }

#pragma unroll
    for (int mf = 0; mf < 4; mf++) {
#pragma unroll
        for (int nf = 0; nf < 4; nf++) {
#pragma unroll
            for (int r = 0; r < 4; r++) {
                const int row = bm * BM + wr * 64 + mf * 16 + (lane >> 4) * 4 + r;
                const int col = bn * BN + wc * 64 + nf * 16 + l15;
                float v = acc[mf][nf][r];
                if (EPI == 0) {
                    float b = (col < 768) ? bias0[col] : bias1[col - 768];
                    Cb[(long)row * N + col] = f2b(v + b);
                } else {
                    Cf[(long)row * N + col] = v + bias0[col];
                }
            }
        }
    }
}

// ---------------- L2 normalize each 96-element segment of each qkv row ----------------
__global__ __launch_bounds__(256) void l2norm_k(unsigned short* __restrict__ qkv) {
    const int tid = threadIdx.x, lane = tid & 63, w = tid >> 6;
    const int g = blockIdx.x * 4 + w;                 // 0 .. 16384*24-1
    const int row = g / 24, seg = g % 24;
    unsigned short* p = qkv + (long)row * 2304 + seg * 96;
    float f0 = 0.f, f1 = 0.f;
    if (lane < 48) {
        unsigned v = *(const unsigned*)(p + lane * 2);
        f0 = b2f((unsigned short)(v & 0xffffu));
        f1 = b2f((unsigned short)(v >> 16));
    }
    float ss = f0 * f0 + f1 * f1;
#pragma unroll
    for (int m = 1; m < 64; m <<= 1) ss += __shfl_xor(ss, m);
    const float sc = 1.f / fmaxf(sqrtf(ss), 1e-12f);
    if (lane < 48) {
        unsigned o = (unsigned)f2b(f0 * sc) | ((unsigned)f2b(f1 * sc) << 16);
        *(unsigned*)(p + lane * 2) = o;
    }
}

// ---------------- fused attention per (bt, head, qtile) ----------------
// Swapped QK^T (S^T = mfma(K,Q)) -> in-register online softmax; P written to LDS
// (overlaying Qs, per-wave row ownership); V staged transposed with key-fast lanes
// (conflict-free scalar writes); PV = mfma(P, V^T).
__global__ __launch_bounds__(256, 4) void attn_k(const unsigned short* __restrict__ qkv,
                                                 unsigned short* __restrict__ obuf) {
    constexpr float SCALE = 0.1020620726159658f;  // 1/sqrt(96)
    __shared__ unsigned short Qs[64 * 104];   // Q tile; reused as P (rows owned per wave)
    __shared__ unsigned short Ks[64 * 104];
    __shared__ unsigned short Vt[96 * 72];    // V^T: rows d (96), cols key (64), pitch 72

    const int tid = threadIdx.x, lane = tid & 63, w = tid >> 6;
    const int bid = blockIdx.x;
    const int qt = bid & 7, h = (bid >> 3) & 7, bt = bid >> 6;
    const long rowbase = (long)bt * 512 * 2304 + h * 96;
    const int l15 = lane & 15;
    const int g = lane >> 4;
    const int ko = g * 8;

    // stage Q tile (64 x 96), coalesced rows
    for (int c = tid; c < 768; c += 256) {
        const int r = c / 12, d8 = (c % 12) * 8;
        *(int4v*)&Qs[r * 104 + d8] = *(const int4v*)&qkv[rowbase + (long)(qt * 64 + r) * 2304 + d8];
    }
    // stage K(0) coalesced, V(0) key-fast transposed
    {
        for (int c = tid; c < 768; c += 256) {
            const int r = c / 12, d8 = (c % 12) * 8;
            *(int4v*)&Ks[r * 104 + d8] = *(const int4v*)&qkv[rowbase + 768 + (long)r * 2304 + d8];
        }
        for (int c = tid; c < 768; c += 256) {
            const int key = c & 63, d8 = (c >> 6) * 8;
            int4v vv = *(const int4v*)&qkv[rowbase + 1536 + (long)key * 2304 + d8];
            const unsigned short* vp = (const unsigned short*)&vv;
#pragma unroll
            for (int i = 0; i < 8; i++) Vt[(d8 + i) * 72 + key] = vp[i];
        }
    }
    __syncthreads();

    // hoist Q fragments (B-operand: rows = q strip, k = d)
    bf16x8 qf[3];
#pragma unroll
    for (int ks = 0; ks < 3; ks++)
        qf[ks] = *(const bf16x8*)&Qs[(w * 16 + l15) * 104 + ks * 32 + ko];

    float m_run = -3.0e38f, l_run = 0.f;
    f32x4 oacc[6] = {};

    for (int kt = 0; kt < 8; kt++) {
        // ---- S^T = mfma(K, Q): rows = key (64), cols = q (lane&15) ----
        f32x4 sacc[4] = {};
#pragma unroll
        for (int ks = 0; ks < 3; ks++) {
#pragma unroll
            for (int kf = 0; kf < 4; kf++) {
                bf16x8 af = *(const bf16x8*)&Ks[(kf * 16 + l15) * 104 + ks * 32 + ko];
                sacc[kf] = __builtin_amdgcn_mfma_f32_16x16x32_bf16(af, qf[ks], sacc[kf], 0, 0, 0);
            }
        }
        // ---- in-register online softmax (lane owns q=l15, keys kf*16+g*4+r) ----
        float p[16];
        float mx = -3.0e38f;
#pragma unroll
        for (int kf = 0; kf < 4; kf++)
#pragma unroll
            for (int r = 0; r < 4; r++) {
                float v = sacc[kf][r] * SCALE;
                p[kf * 4 + r] = v;
                mx = fmaxf(mx, v);
            }
        mx = fmaxf(mx, __shfl_xor(mx, 16));
        mx = fmaxf(mx, __shfl_xor(mx, 32));
        const float mnew = fmaxf(m_run, mx);
        const float al = __expf(m_run - mnew);
        float s = 0.f;
#pragma unroll
        for (int i = 0; i < 16; i++) {
            p[i] = __expf(p[i] - mnew);
            s += p[i];
        }
        s += __shfl_xor(s, 16);
        s += __shfl_xor(s, 32);
        l_run = l_run * al + s;
        m_run = mnew;
        // rescale O accumulators (alpha for q = g*4+r lives on lane g*4+r)
        float alr[4];
#pragma unroll
        for (int r = 0; r < 4; r++) alr[r] = __shfl(al, g * 4 + r);
#pragma unroll
        for (int nf = 0; nf < 6; nf++)
#pragma unroll
            for (int r = 0; r < 4; r++) oacc[nf][r] *= alr[r];
        // ---- write P (row q = w*16+l15, cols keys) into Qs region, paired u32 ----
        {
            unsigned* prow = (unsigned*)&Qs[(w * 16 + l15) * 104];
#pragma unroll
            for (int kf = 0; kf < 4; kf++)
#pragma unroll
                for (int rp = 0; rp < 2; rp++) {
                    unsigned pk = (unsigned)f2b(p[kf * 4 + 2 * rp]) |
                                  ((unsigned)f2b(p[kf * 4 + 2 * rp + 1]) << 16);
                    prow[kf * 8 + g * 2 + rp] = pk;
                }
        }
        // ---- O += P * V  (A = P rows q, B = V^T rows d) ----
#pragma unroll
        for (int ks = 0; ks < 2; ks++) {
            bf16x8 pa = *(const bf16x8*)&Qs[(w * 16 + l15) * 104 + ks * 32 + ko];
#pragma unroll
            for (int nf = 0; nf < 6; nf++) {
                bf16x8 vb = *(const bf16x8*)&Vt[(nf * 16 + l15) * 72 + ks * 32 + ko];
                oacc[nf] = __builtin_amdgcn_mfma_f32_16x16x32_bf16(pa, vb, oacc[nf], 0, 0, 0);
            }
        }
        __syncthreads();
        if (kt < 7) {
            const int kn = kt + 1;
            for (int c = tid; c < 768; c += 256) {
                const int r = c / 12, d8 = (c % 12) * 8;
                *(int4v*)&Ks[r * 104 + d8] = *(const int4v*)&qkv[rowbase + 768 + (long)(kn * 64 + r) * 2304 + d8];
            }
            for (int c = tid; c < 768; c += 256) {
                const int key = c & 63, d8 = (c >> 6) * 8;
                int4v vv = *(const int4v*)&qkv[rowbase + 1536 + (long)(kn * 64 + key) * 2304 + d8];
                const unsigned short* vp = (const unsigned short*)&vv;
#pragma unroll
                for (int i = 0; i < 8; i++) Vt[(d8 + i) * 72 + key] = vp[i];
            }
            __syncthreads();
        }
    }

    // ---- write O tile ----
    const float inv = 1.f / l_run;
    float invr[4];
#pragma unroll
    for (int r = 0; r < 4; r++) invr[r] = __shfl(inv, g * 4 + r);
#pragma unroll
    for (int r = 0; r < 4; r++) {
        const int row = w * 16 + g * 4 + r;
        const long gr = ((long)(bt * 512 + qt * 64 + row)) * 768 + h * 96;
#pragma unroll
        for (int nf = 0; nf < 6; nf++)
            obuf[gr + nf * 16 + l15] = f2b(oacc[nf][r] * invr[r]);
    }
}

extern "C" void kernel_launch(void* const* d_in, const int* in_sizes, int n_in,
                              void* d_out, int out_size, void* d_ws, size_t ws_size,
                              hipStream_t stream) {
    const float* x   = (const float*)d_in[0];
    const float* Wq  = (const float*)d_in[1];
    const float* bq  = (const float*)d_in[2];
    const float* Wkv = (const float*)d_in[3];
    const float* bkv = (const float*)d_in[4];
    const float* Wm  = (const float*)d_in[5];
    const float* bm  = (const float*)d_in[6];
    float* out = (float*)d_out;

    char* ws = (char*)d_ws;
    unsigned short* xb  = (unsigned short*)ws;                   // 16384x768 bf16  = 25165824 B
    unsigned short* wt  = (unsigned short*)(ws + 25165824);      // 3072x768 bf16   =  4718592 B
    unsigned short* qkv = (unsigned short*)(ws + 29884416);      // 16384x2304 bf16 = 75497472 B
    unsigned short* ob  = (unsigned short*)(ws + 105381888);     // 16384x768 bf16  = 25165824 B

    cast_bf16_k<<<dim3(12288), dim3(256), 0, stream>>>(x, xb, 3145728);
    pack_w_k<<<dim3(576), dim3(256), 0, stream>>>(Wq, Wkv, Wm, wt);
    gemm_bt_k<0><<<dim3(128 * 18), dim3(256), 0, stream>>>(xb, wt, bq, bkv, qkv, nullptr, 16384, 2304, 768);
    l2norm_k<<<dim3(98304), dim3(256), 0, stream>>>(qkv);
    attn_k<<<dim3(2048), dim3(256), 0, stream>>>(qkv, ob);
    gemm_bt_k<1><<<dim3(128 * 6), dim3(256), 0, stream>>>(ob, wt + (long)2304 * 768, bm, nullptr, nullptr, out, 16384, 768, 768);
}

// Round 3
// 259.610 us; speedup vs baseline: 1.3223x; 1.0596x over previous
//
#include <hip/hip_runtime.h>
#include <hip/hip_bf16.h>

// Problem constants: B=4,T=8,L=512,C=768,H=8,HD=96.  M = B*T*L = 16384.

typedef __attribute__((ext_vector_type(8))) short bf16x8;
typedef __attribute__((ext_vector_type(4))) float f32x4;
typedef __attribute__((ext_vector_type(4))) int int4v;

__device__ __forceinline__ float b2f(unsigned short u) {
    return __uint_as_float(((unsigned)u) << 16);
}
__device__ __forceinline__ unsigned short f2b(float f) {
    unsigned u = __float_as_uint(f);
    u = (u + 0x7fffu + ((u >> 16) & 1u)) >> 16;   // RNE
    return (unsigned short)u;
}

__device__ __forceinline__ void gll16(const unsigned short* g, unsigned short* l) {
    __builtin_amdgcn_global_load_lds((const __attribute__((address_space(1))) unsigned int*)g,
                                     (__attribute__((address_space(3))) unsigned int*)l, 16, 0, 0);
}

#define VMCNT(n) asm volatile("s_waitcnt vmcnt(" #n ")" ::: "memory")
#define BAR()    __builtin_amdgcn_s_barrier()
#define SCHED0() __builtin_amdgcn_sched_barrier(0)
#define PRIO(x)  __builtin_amdgcn_s_setprio(x)

// ---------------- cast x (fp32) -> bf16 ----------------
__global__ __launch_bounds__(256) void cast_bf16_k(const float* __restrict__ x,
                                                   unsigned short* __restrict__ xb, int n4) {
    int i = blockIdx.x * 256 + threadIdx.x;
    if (i >= n4) return;
    float4 v = ((const float4*)x)[i];
    ushort4 o;
    o.x = f2b(v.x); o.y = f2b(v.y); o.z = f2b(v.z); o.w = f2b(v.w);
    ((ushort4*)xb)[i] = o;
}

// ---------------- pack weights: Wt[n][k] = W[k][n] (bf16), n in [0,3072) ----------------
__global__ __launch_bounds__(256) void pack_w_k(const float* __restrict__ Wq,
                                                const float* __restrict__ Wkv,
                                                const float* __restrict__ Wm,
                                                unsigned short* __restrict__ Wt) {
    __shared__ float tile[64][65];
    const int tid = threadIdx.x;
    const int tn = blockIdx.x % 48;
    const int tk = blockIdx.x / 48;
    const int n0 = tn * 64, k0 = tk * 64;
    const float* src; int ldn, coff;
    if (n0 < 768)       { src = Wq;  ldn = 768;  coff = n0; }
    else if (n0 < 2304) { src = Wkv; ldn = 1536; coff = n0 - 768; }
    else                { src = Wm;  ldn = 768;  coff = n0 - 2304; }
    const int j = tid & 63;
    for (int i = tid >> 6; i < 64; i += 4)
        tile[i][j] = src[(k0 + i) * ldn + coff + j];
    __syncthreads();
    const int ii = tid & 63;
    for (int jj = tid >> 6; jj < 64; jj += 4)
        Wt[(long)(n0 + jj) * 768 + k0 + ii] = f2b(tile[ii][jj]);
}

// ---------------- 256x256 pipelined GEMM: C = A(MxK) * Bt(NxK)^T + bias ----------------
// 512 threads = 8 waves (2M x 4N), per-wave 128x64 output, BK=64, 128 KiB LDS dbuf.
// LDS swizzle: 16B chunk c of row stored at c ^ (row&7); staged via pre-swizzled
// global source (global_load_lds writes linearly). Counted vmcnt, raw barriers.
// EPI 0: bf16 out, bias = col<768 ? bias0[col] : bias1[col-768]
// EPI 1: fp32 out, bias = bias0[col]
template <int EPI>
__global__ __launch_bounds__(512, 2) void gemm256_k(const unsigned short* __restrict__ A,
                                                    const unsigned short* __restrict__ Bt,
                                                    const float* __restrict__ bias0,
                                                    const float* __restrict__ bias1,
                                                    unsigned short* __restrict__ Cb,
                                                    float* __restrict__ Cf,
                                                    int M, int N, int K, int nbn) {
    extern __shared__ unsigned short lds[];   // 131072 B: buf p: A at p*32768, B at p*32768+16384 (ushort idx)
    const int tid = threadIdx.x;
    const int lane = tid & 63, wid = tid >> 6;
    const int wm = wid >> 2, wn = wid & 3;
    const int l15 = lane & 15, g = lane >> 4;

    // XCD-bijective swizzle (grid % 8 == 0 by construction)
    const int nwg = gridDim.x;
    const int wg = (blockIdx.x & 7) * (nwg >> 3) + (blockIdx.x >> 3);
    const int bm = wg / nbn, bn = wg % nbn;

    const unsigned short* gA = A  + (long)bm * 256 * K;
    const unsigned short* gB = Bt + (long)bn * 256 * K;

    // staging geometry: one "issue" = 512 threads x 16B = 64 rows (8 chunks/row)
    const int srow = tid >> 3;
    const int ssc = (tid & 7) ^ (srow & 7);          // pre-swizzled source chunk
    const long sgoff = (long)srow * K + ssc * 8;     // + R0*K + kt*64
    const int sloff = (tid & 448) * 8;               // + R0*64  (ushort units)

#define STAGE(GB, LB, R0) gll16((GB) + (long)(R0) * K + sgoff, (LB) + (R0) * 64 + sloff)

    // fragment read addressing (ushort units): row*64 + xc*8, xc = (kk*4+g)^(l15&7)
    const int axc0 = ((0 * 4 + g) ^ (l15 & 7)) * 8;
    const int axc1 = ((1 * 4 + g) ^ (l15 & 7)) * 8;
    const int arow = (wm * 128 + l15) * 64;
    const int brow = (wn * 64 + l15) * 64;

#define READ_A(MQ, PTR) \
    _Pragma("unroll") for (int mf = 0; mf < 4; mf++) { \
        af[mf][0] = *(const bf16x8*)&(PTR)[arow + ((MQ) * 64 + mf * 16) * 64 + axc0]; \
        af[mf][1] = *(const bf16x8*)&(PTR)[arow + ((MQ) * 64 + mf * 16) * 64 + axc1]; \
    }
#define READ_B(NQ, PTR) \
    _Pragma("unroll") for (int nf = 0; nf < 2; nf++) { \
        bf[nf][0] = *(const bf16x8*)&(PTR)[brow + ((NQ) * 32 + nf * 16) * 64 + axc0]; \
        bf[nf][1] = *(const bf16x8*)&(PTR)[brow + ((NQ) * 32 + nf * 16) * 64 + axc1]; \
    }
#define DO_PHASE(MQ, NQ) \
    PRIO(1); \
    _Pragma("unroll") for (int mf = 0; mf < 4; mf++) \
    _Pragma("unroll") for (int nf = 0; nf < 2; nf++) \
    _Pragma("unroll") for (int kk = 0; kk < 2; kk++) \
        acc[(MQ) * 4 + mf][(NQ) * 2 + nf] = __builtin_amdgcn_mfma_f32_16x16x32_bf16( \
            af[mf][kk], bf[nf][kk], acc[(MQ) * 4 + mf][(NQ) * 2 + nf], 0, 0, 0); \
    PRIO(0);

    f32x4 acc[8][4] = {};
    const int nkt = K >> 6;

    // prologue: stage tile 0 into buf0, order [B0,B1,B2,B3, A0,A2, A1,A3]
    {
        unsigned short* lA = lds;
        unsigned short* lB = lds + 16384;
        STAGE(gB, lB, 0); STAGE(gB, lB, 64); STAGE(gB, lB, 128); STAGE(gB, lB, 192);
        STAGE(gA, lA, 0); STAGE(gA, lA, 128); STAGE(gA, lA, 64); STAGE(gA, lA, 192);
    }

    for (int t = 0; t < nkt; ++t) {
        unsigned short* curA = lds + (t & 1) * 32768;
        unsigned short* curB = curA + 16384;
        unsigned short* nxtA = lds + ((t + 1) & 1) * 32768;
        unsigned short* nxtB = nxtA + 16384;
        const unsigned short* gAn = gA + (t + 1) * 64;
        const unsigned short* gBn = gB + (t + 1) * 64;
        const bool pf = (t + 1 < nkt);

        // boundary gate: tile-t B*, A0, A2 landed (6 oldest of 8)
        VMCNT(2); BAR(); SCHED0();

        bf16x8 af[4][2], bf[2][2];
        // P0
        if (pf) { STAGE(gBn, nxtB, 0); STAGE(gBn, nxtB, 64); }
        READ_A(0, curA);
        READ_B(0, curB);
        DO_PHASE(0, 0);
        // P1
        if (pf) { STAGE(gBn, nxtB, 128); STAGE(gBn, nxtB, 192); }
        READ_B(1, curB);
        DO_PHASE(0, 1);
        // mid gate: tile-t A1, A3 landed (2 oldest of <=6)
        VMCNT(4); BAR(); SCHED0();
        // P2
        if (pf) { STAGE(gAn, nxtA, 0); STAGE(gAn, nxtA, 128); }
        READ_A(1, curA);
        READ_B(0, curB);
        DO_PHASE(1, 0);
        // P3
        if (pf) { STAGE(gAn, nxtA, 64); STAGE(gAn, nxtA, 192); }
        READ_B(1, curB);
        DO_PHASE(1, 1);
    }

    // ---------------- epilogue ----------------
    float bv[4];
#pragma unroll
    for (int nf = 0; nf < 4; nf++) {
        const int col = bn * 256 + wn * 64 + nf * 16 + l15;
        bv[nf] = (EPI == 0) ? ((col < 768) ? bias0[col] : bias1[col - 768]) : bias0[col];
    }
#pragma unroll
    for (int MF = 0; MF < 8; MF++) {
#pragma unroll
        for (int r = 0; r < 4; r++) {
            const long row = bm * 256 + wm * 128 + MF * 16 + g * 4 + r;
#pragma unroll
            for (int nf = 0; nf < 4; nf++) {
                const float v = acc[MF][nf][r] + bv[nf];
                if (EPI == 0) {
                    const unsigned h = f2b(v);
                    const unsigned o = __shfl_xor((int)h, 1);
                    if (!(lane & 1))
                        *(unsigned*)&Cb[row * N + bn * 256 + wn * 64 + nf * 16 + l15] =
                            (h & 0xffffu) | (o << 16);
                } else {
                    Cf[row * N + bn * 256 + wn * 64 + nf * 16 + l15] = v;
                }
            }
        }
    }
#undef STAGE
#undef READ_A
#undef READ_B
#undef DO_PHASE
}

// ---------------- L2 normalize each 96-element segment of each qkv row ----------------
__global__ __launch_bounds__(256) void l2norm_k(unsigned short* __restrict__ qkv) {
    const int tid = threadIdx.x, lane = tid & 63, w = tid >> 6;
    const int g = blockIdx.x * 4 + w;
    const int row = g / 24, seg = g % 24;
    unsigned short* p = qkv + (long)row * 2304 + seg * 96;
    float f0 = 0.f, f1 = 0.f;
    if (lane < 48) {
        unsigned v = *(const unsigned*)(p + lane * 2);
        f0 = b2f((unsigned short)(v & 0xffffu));
        f1 = b2f((unsigned short)(v >> 16));
    }
    float ss = f0 * f0 + f1 * f1;
#pragma unroll
    for (int m = 1; m < 64; m <<= 1) ss += __shfl_xor(ss, m);
    const float sc = 1.f / fmaxf(sqrtf(ss), 1e-12f);
    if (lane < 48) {
        unsigned o = (unsigned)f2b(f0 * sc) | ((unsigned)f2b(f1 * sc) << 16);
        *(unsigned*)(p + lane * 2) = o;
    }
}

// ---------------- fused attention per (bt, head, qtile) ----------------
__global__ __launch_bounds__(256, 4) void attn_k(const unsigned short* __restrict__ qkv,
                                                 unsigned short* __restrict__ obuf) {
    constexpr float SCALE = 0.1020620726159658f;  // 1/sqrt(96)
    __shared__ unsigned short Qs[64 * 104];   // Q tile; reused as P (rows owned per wave)
    __shared__ unsigned short Ks[64 * 104];
    __shared__ unsigned short Vt[96 * 72];    // V^T: rows d (96), cols key (64), pitch 72

    const int tid = threadIdx.x, lane = tid & 63, w = tid >> 6;
    const int bid0 = blockIdx.x;
    const int bid = (bid0 & 7) * 256 + (bid0 >> 3);   // XCD swizzle (2048 % 8 == 0)
    const int qt = bid & 7, h = (bid >> 3) & 7, bt = bid >> 6;
    const long rowbase = (long)bt * 512 * 2304 + h * 96;
    const int l15 = lane & 15;
    const int g = lane >> 4;
    const int ko = g * 8;

    for (int c = tid; c < 768; c += 256) {
        const int r = c / 12, d8 = (c % 12) * 8;
        *(int4v*)&Qs[r * 104 + d8] = *(const int4v*)&qkv[rowbase + (long)(qt * 64 + r) * 2304 + d8];
    }
    {
        for (int c = tid; c < 768; c += 256) {
            const int r = c / 12, d8 = (c % 12) * 8;
            *(int4v*)&Ks[r * 104 + d8] = *(const int4v*)&qkv[rowbase + 768 + (long)r * 2304 + d8];
        }
        for (int c = tid; c < 768; c += 256) {
            const int key = c & 63, d8 = (c >> 6) * 8;
            int4v vv = *(const int4v*)&qkv[rowbase + 1536 + (long)key * 2304 + d8];
            const unsigned short* vp = (const unsigned short*)&vv;
#pragma unroll
            for (int i = 0; i < 8; i++) Vt[(d8 + i) * 72 + key] = vp[i];
        }
    }
    __syncthreads();

    bf16x8 qf[3];
#pragma unroll
    for (int ks = 0; ks < 3; ks++)
        qf[ks] = *(const bf16x8*)&Qs[(w * 16 + l15) * 104 + ks * 32 + ko];

    float m_run = -3.0e38f, l_run = 0.f;
    f32x4 oacc[6] = {};

    for (int kt = 0; kt < 8; kt++) {
        f32x4 sacc[4] = {};
#pragma unroll
        for (int ks = 0; ks < 3; ks++) {
#pragma unroll
            for (int kf = 0; kf < 4; kf++) {
                bf16x8 af = *(const bf16x8*)&Ks[(kf * 16 + l15) * 104 + ks * 32 + ko];
                sacc[kf] = __builtin_amdgcn_mfma_f32_16x16x32_bf16(af, qf[ks], sacc[kf], 0, 0, 0);
            }
        }
        float p[16];
        float mx = -3.0e38f;
#pragma unroll
        for (int kf = 0; kf < 4; kf++)
#pragma unroll
            for (int r = 0; r < 4; r++) {
                float v = sacc[kf][r] * SCALE;
                p[kf * 4 + r] = v;
                mx = fmaxf(mx, v);
            }
        mx = fmaxf(mx, __shfl_xor(mx, 16));
        mx = fmaxf(mx, __shfl_xor(mx, 32));
        const float mnew = fmaxf(m_run, mx);
        const float al = __expf(m_run - mnew);
        float s = 0.f;
#pragma unroll
        for (int i = 0; i < 16; i++) {
            p[i] = __expf(p[i] - mnew);
            s += p[i];
        }
        s += __shfl_xor(s, 16);
        s += __shfl_xor(s, 32);
        l_run = l_run * al + s;
        m_run = mnew;
        float alr[4];
#pragma unroll
        for (int r = 0; r < 4; r++) alr[r] = __shfl(al, g * 4 + r);
#pragma unroll
        for (int nf = 0; nf < 6; nf++)
#pragma unroll
            for (int r = 0; r < 4; r++) oacc[nf][r] *= alr[r];
        {
            unsigned* prow = (unsigned*)&Qs[(w * 16 + l15) * 104];
#pragma unroll
            for (int kf = 0; kf < 4; kf++)
#pragma unroll
                for (int rp = 0; rp < 2; rp++) {
                    unsigned pk = (unsigned)f2b(p[kf * 4 + 2 * rp]) |
                                  ((unsigned)f2b(p[kf * 4 + 2 * rp + 1]) << 16);
                    prow[kf * 8 + g * 2 + rp] = pk;
                }
        }
#pragma unroll
        for (int ks = 0; ks < 2; ks++) {
            bf16x8 pa = *(const bf16x8*)&Qs[(w * 16 + l15) * 104 + ks * 32 + ko];
#pragma unroll
            for (int nf = 0; nf < 6; nf++) {
                bf16x8 vb = *(const bf16x8*)&Vt[(nf * 16 + l15) * 72 + ks * 32 + ko];
                oacc[nf] = __builtin_amdgcn_mfma_f32_16x16x32_bf16(pa, vb, oacc[nf], 0, 0, 0);
            }
        }
        __syncthreads();
        if (kt < 7) {
            const int kn = kt + 1;
            for (int c = tid; c < 768; c += 256) {
                const int r = c / 12, d8 = (c % 12) * 8;
                *(int4v*)&Ks[r * 104 + d8] = *(const int4v*)&qkv[rowbase + 768 + (long)(kn * 64 + r) * 2304 + d8];
            }
            for (int c = tid; c < 768; c += 256) {
                const int key = c & 63, d8 = (c >> 6) * 8;
                int4v vv = *(const int4v*)&qkv[rowbase + 1536 + (long)(kn * 64 + key) * 2304 + d8];
                const unsigned short* vp = (const unsigned short*)&vv;
#pragma unroll
                for (int i = 0; i < 8; i++) Vt[(d8 + i) * 72 + key] = vp[i];
            }
            __syncthreads();
        }
    }

    const float inv = 1.f / l_run;
    float invr[4];
#pragma unroll
    for (int r = 0; r < 4; r++) invr[r] = __shfl(inv, g * 4 + r);
#pragma unroll
    for (int r = 0; r < 4; r++) {
        const int row = w * 16 + g * 4 + r;
        const long gr = ((long)(bt * 512 + qt * 64 + row)) * 768 + h * 96;
#pragma unroll
        for (int nf = 0; nf < 6; nf++)
            obuf[gr + nf * 16 + l15] = f2b(oacc[nf][r] * invr[r]);
    }
}

extern "C" void kernel_launch(void* const* d_in, const int* in_sizes, int n_in,
                              void* d_out, int out_size, void* d_ws, size_t ws_size,
                              hipStream_t stream) {
    const float* x   = (const float*)d_in[0];
    const float* Wq  = (const float*)d_in[1];
    const float* bq  = (const float*)d_in[2];
    const float* Wkv = (const float*)d_in[3];
    const float* bkv = (const float*)d_in[4];
    const float* Wm  = (const float*)d_in[5];
    const float* bm  = (const float*)d_in[6];
    float* out = (float*)d_out;

    char* ws = (char*)d_ws;
    unsigned short* xb  = (unsigned short*)ws;                   // 16384x768 bf16
    unsigned short* wt  = (unsigned short*)(ws + 25165824);      // 3072x768 bf16
    unsigned short* qkv = (unsigned short*)(ws + 29884416);      // 16384x2304 bf16
    unsigned short* ob  = (unsigned short*)(ws + 105381888);     // 16384x768 bf16

    static bool attr_set = false;
    if (!attr_set) {
        hipFuncSetAttribute((const void*)gemm256_k<0>, hipFuncAttributeMaxDynamicSharedMemorySize, 131072);
        hipFuncSetAttribute((const void*)gemm256_k<1>, hipFuncAttributeMaxDynamicSharedMemorySize, 131072);
        attr_set = true;
    }

    cast_bf16_k<<<dim3(12288), dim3(256), 0, stream>>>(x, xb, 3145728);
    pack_w_k<<<dim3(576), dim3(256), 0, stream>>>(Wq, Wkv, Wm, wt);
    // QKV projection + bias: grid 64 x 9 = 576
    gemm256_k<0><<<dim3(576), dim3(512), 131072, stream>>>(xb, wt, bq, bkv, qkv, nullptr, 16384, 2304, 768, 9);
    l2norm_k<<<dim3(98304), dim3(256), 0, stream>>>(qkv);
    attn_k<<<dim3(2048), dim3(256), 0, stream>>>(qkv, ob);
    // output projection + bias -> fp32: grid 64 x 3 = 192
    gemm256_k<1><<<dim3(192), dim3(512), 131072, stream>>>(ob, wt + (long)2304 * 768, bm, nullptr, nullptr, out, 16384, 768, 768, 3);
}